// Round 6
// baseline (158.061 us; speedup 1.0000x reference)
//
#include <hip/hip_runtime.h>

#define T_SEQ 2048
#define C_DIM 128
#define S_QK 0.08838834764831845f

typedef __attribute__((ext_vector_type(8))) short bf16x8;
typedef __attribute__((ext_vector_type(4))) float f32x4;

// ---- workspace layout (bytes) ----
// qw  bf16 [8][2048][128]   @ 0
// kw  bf16 [8][2048][128]   @ 4,194,304
// vw  bf16 [8][128][2048]   @ 8,388,608   (V^T)
// opart bf16 [576][64][128] @ 12,582,912  (9,437,184 B)
// ml  float2 [576][64]      @ 22,020,096  (294,912 B)    total ~22.3 MB
#define ML_OFF 22020096UL

__device__ __forceinline__ unsigned short f2bf(float f) {
    union { float f; unsigned int u; } v; v.f = f;
    unsigned int r = v.u + 0x7FFFu + ((v.u >> 16) & 1u);
    return (unsigned short)(r >> 16);
}

// slot base within a batch for qt>=8, chunks of 8 key-tiles (72 slots/batch)
__device__ __forceinline__ int chunk_base8(int qt) {
    int g = qt >> 3;                       // 1,2,3
    if (g == 1) return (qt - 8) * 2;
    if (g == 2) return 16 + (qt - 16) * 3;
    return 40 + (qt - 24) * 4;
}

// ---------------------------------------------------------------------------
// proj: z-split. grid 768 (1D): bid = b + 8*(tile + 32*z) -> batch pinned to
// XCD, 3 blocks/CU co-resident. fp32->bf16 fused into staging (scale into Wq).
// ---------------------------------------------------------------------------
__global__ __launch_bounds__(256) void proj_kernel(
    const float* __restrict__ x,
    const float* __restrict__ Wq, const float* __restrict__ Wk,
    const float* __restrict__ Wv,
    unsigned short* __restrict__ qo, unsigned short* __restrict__ ko,
    unsigned short* __restrict__ vto)
{
    const int bid  = blockIdx.x;
    const int b    = bid & 7;
    const int r2   = bid >> 3;             // 0..95
    const int tile = r2 & 31;              // 64-row tile within batch
    const int z    = r2 >> 5;              // 0=q, 1=k, 2=v(transposed)
    const int rt   = b * 32 + tile;
    const int tid  = threadIdx.x;
    const int lane = tid & 63;
    const int w    = tid >> 6;
    const int n16  = lane & 15;
    const int quad = lane >> 4;

    __shared__ __align__(16) unsigned short Wl[128 * 136];   // 34816 B (also epilogue stage)
    __shared__ __align__(16) unsigned short Xl[64 * 136];    // 17408 B

    const float* W = (z == 0) ? Wq : (z == 1) ? Wk : Wv;
    const float scale = (z == 0) ? S_QK : 1.0f;

    // ---- stage W (fp32 -> bf16, scaled) ----
    #pragma unroll
    for (int i = 0; i < 16; ++i) {
        int e = (tid + i * 256) * 4;
        int r = e >> 7, c = e & 127;
        float4 v = *reinterpret_cast<const float4*>(W + e);
        ushort4 o4;
        o4.x = f2bf(v.x * scale); o4.y = f2bf(v.y * scale);
        o4.z = f2bf(v.z * scale); o4.w = f2bf(v.w * scale);
        *reinterpret_cast<ushort4*>(&Wl[r * 136 + c]) = o4;
    }
    // ---- stage x tile ----
    const float* xr = x + (size_t)rt * 64 * C_DIM;
    #pragma unroll
    for (int i = 0; i < 8; ++i) {
        int e = (tid + i * 256) * 4;
        int r = e >> 7, c = e & 127;
        float4 v = *reinterpret_cast<const float4*>(xr + e);
        ushort4 o4;
        o4.x = f2bf(v.x); o4.y = f2bf(v.y); o4.z = f2bf(v.z); o4.w = f2bf(v.w);
        *reinterpret_cast<ushort4*>(&Xl[r * 136 + c]) = o4;
    }
    __syncthreads();

    bf16x8 afr[4];
    #pragma unroll
    for (int kk = 0; kk < 4; ++kk)
        afr[kk] = *reinterpret_cast<const bf16x8*>(
            &Xl[(w * 16 + n16) * 136 + kk * 32 + quad * 8]);

    f32x4 acc[8];
    #pragma unroll
    for (int nt = 0; nt < 8; ++nt) acc[nt] = (f32x4){0.f, 0.f, 0.f, 0.f};
    #pragma unroll
    for (int kk = 0; kk < 4; ++kk)
        #pragma unroll
        for (int nt = 0; nt < 8; ++nt) {
            bf16x8 bfr = *reinterpret_cast<const bf16x8*>(
                &Wl[(nt * 16 + n16) * 136 + kk * 32 + quad * 8]);
            acc[nt] = __builtin_amdgcn_mfma_f32_16x16x32_bf16(afr[kk], bfr, acc[nt], 0, 0, 0);
        }
    __syncthreads();                       // all waves done reading Wl

    if (z < 2) {
        // per-wave 16x128 stage in Wl, then fully-contiguous 1-KB stores
        unsigned short* os = Wl + w * 2048;
        #pragma unroll
        for (int nt = 0; nt < 8; ++nt)
            #pragma unroll
            for (int r = 0; r < 4; ++r)
                os[(quad * 4 + r) * 128 + nt * 16 + n16] = f2bf(acc[nt][r]);
        unsigned short* dst = (z == 0 ? qo : ko) + (size_t)(rt * 64 + w * 16) * C_DIM;
        #pragma unroll
        for (int i = 0; i < 4; ++i) {
            int e = (lane + i * 64) * 8;
            *reinterpret_cast<uint4*>(dst + e) =
                *reinterpret_cast<const uint4*>(os + e);
        }
    } else {
        // whole-block [128 d][64 t] stage (stride 72), then 128-B rows
        unsigned short* os = Wl;
        #pragma unroll
        for (int nt = 0; nt < 8; ++nt)
            #pragma unroll
            for (int r = 0; r < 4; ++r)
                os[(nt * 16 + n16) * 72 + w * 16 + quad * 4 + r] = f2bf(acc[nt][r]);
        __syncthreads();
        unsigned short* dst = vto + (size_t)b * C_DIM * T_SEQ + tile * 64;
        #pragma unroll
        for (int i = 0; i < 4; ++i) {
            int e = tid + i * 256;         // 1024 chunks: d = e>>3, seg = e&7
            int d = e >> 3, seg = (e & 7) * 8;
            *reinterpret_cast<uint4*>(dst + (size_t)d * T_SEQ + seg) =
                *reinterpret_cast<const uint4*>(os + d * 72 + seg);
        }
    }
}

// ---------------------------------------------------------------------------
// attn pass 1: split-K flash attention, LDS-staged K/V + register prefetch.
// grid 1024 (1D): bid = b + 8*(qt + 32*chunk), chunk = 8 key-tiles (640
// active blocks, all co-resident at 3/CU). qt<8 writes final output;
// else bf16 partial (contiguous 1-KB stores via Kl reuse) + (m,l).
// ---------------------------------------------------------------------------
__global__ __launch_bounds__(256) void attn_kernel(
    const unsigned short* __restrict__ qb,
    const unsigned short* __restrict__ kb,
    const unsigned short* __restrict__ vtb,
    unsigned short* __restrict__ opart, float2* __restrict__ mlbuf,
    float* __restrict__ out)
{
    const int bid   = blockIdx.x;
    const int b     = bid & 7;
    const int t2    = bid >> 3;
    const int qt    = t2 & 31;
    const int chunk = t2 >> 5;
    if (chunk * 8 > qt) return;

    const int tid  = threadIdx.x;
    const int lane = tid & 63;
    const int w    = tid >> 6;
    const int n16  = lane & 15;
    const int quad = lane >> 4;

    __shared__ __align__(16) unsigned short Kl[64 * 136];    // 17408 B (also epilogue stage)
    __shared__ __align__(16) unsigned short Vl[128 * 72];    // 18432 B
    __shared__ __align__(16) unsigned short Pl[4][16 * 72];  //  9216 B

    const size_t bT = (size_t)b * T_SEQ;
    const int qbase = qt * 64 + w * 16;

    bf16x8 qfr[4];
    #pragma unroll
    for (int kk = 0; kk < 4; ++kk)
        qfr[kk] = *reinterpret_cast<const bf16x8*>(
            qb + (bT + qbase + n16) * C_DIM + kk * 32 + quad * 8);

    f32x4 o[8];
    #pragma unroll
    for (int ct = 0; ct < 8; ++ct) o[ct] = (f32x4){0.f, 0.f, 0.f, 0.f};
    float m[4], l[4];
    #pragma unroll
    for (int r = 0; r < 4; ++r) { m[r] = -INFINITY; l[r] = 0.f; }

    const int k0 = chunk * 8;
    const int k1 = min(k0 + 8, qt + 1);
    const unsigned short* vbase = vtb + (size_t)b * C_DIM * T_SEQ;

    // ---- prologue: tile k0 -> registers ----
    uint4 kreg[4], vreg[4];
    {
        const unsigned short* ks = kb + (bT + (size_t)k0 * 64) * C_DIM;
        #pragma unroll
        for (int i = 0; i < 4; ++i) {
            int e = tid + i * 256;
            kreg[i] = *reinterpret_cast<const uint4*>(ks + (e >> 4) * 128 + (e & 15) * 8);
        }
        const unsigned short* vs = vbase + (size_t)k0 * 64;
        #pragma unroll
        for (int i = 0; i < 4; ++i) {
            int e = tid + i * 256;
            vreg[i] = *reinterpret_cast<const uint4*>(vs + (size_t)(e >> 3) * T_SEQ + (e & 7) * 8);
        }
    }

    for (int kt = k0; kt < k1; ++kt) {
        __syncthreads();                   // prev iter's LDS reads done
        #pragma unroll
        for (int i = 0; i < 4; ++i) {
            int e = tid + i * 256;
            *reinterpret_cast<uint4*>(&Kl[(e >> 4) * 136 + (e & 15) * 8]) = kreg[i];
        }
        #pragma unroll
        for (int i = 0; i < 4; ++i) {
            int e = tid + i * 256;
            *reinterpret_cast<uint4*>(&Vl[(e >> 3) * 72 + (e & 7) * 8]) = vreg[i];
        }
        __syncthreads();

        // prefetch next tile (covered by compute below)
        if (kt + 1 < k1) {
            const unsigned short* ks = kb + (bT + (size_t)(kt + 1) * 64) * C_DIM;
            #pragma unroll
            for (int i = 0; i < 4; ++i) {
                int e = tid + i * 256;
                kreg[i] = *reinterpret_cast<const uint4*>(ks + (e >> 4) * 128 + (e & 15) * 8);
            }
            const unsigned short* vs = vbase + (size_t)(kt + 1) * 64;
            #pragma unroll
            for (int i = 0; i < 4; ++i) {
                int e = tid + i * 256;
                vreg[i] = *reinterpret_cast<const uint4*>(vs + (size_t)(e >> 3) * T_SEQ + (e & 7) * 8);
            }
        }

        // ---- S = Q K^T ----
        f32x4 s[4];
        #pragma unroll
        for (int nt = 0; nt < 4; ++nt) s[nt] = (f32x4){0.f, 0.f, 0.f, 0.f};
        #pragma unroll
        for (int kk = 0; kk < 4; ++kk)
            #pragma unroll
            for (int nt = 0; nt < 4; ++nt) {
                bf16x8 kf = *reinterpret_cast<const bf16x8*>(
                    &Kl[(nt * 16 + n16) * 136 + kk * 32 + quad * 8]);
                s[nt] = __builtin_amdgcn_mfma_f32_16x16x32_bf16(qfr[kk], kf, s[nt], 0, 0, 0);
            }

        if (kt == qt) {                    // causal mask on diagonal tile
            #pragma unroll
            for (int nt = 0; nt < 4; ++nt)
                #pragma unroll
                for (int r = 0; r < 4; ++r) {
                    int sabs = kt * 64 + nt * 16 + n16;
                    int qabs = qbase + quad * 4 + r;
                    if (sabs > qabs) s[nt][r] = -1e30f;
                }
        }

        // ---- online softmax ----
        float alpha[4];
        #pragma unroll
        for (int r = 0; r < 4; ++r) {
            float tmax = fmaxf(fmaxf(s[0][r], s[1][r]), fmaxf(s[2][r], s[3][r]));
            #pragma unroll
            for (int off = 1; off < 16; off <<= 1)
                tmax = fmaxf(tmax, __shfl_xor(tmax, off));
            float mn = fmaxf(m[r], tmax);
            alpha[r] = __expf(m[r] - mn);
            float tsum = 0.f;
            #pragma unroll
            for (int nt = 0; nt < 4; ++nt) {
                float p = __expf(s[nt][r] - mn);
                s[nt][r] = p;
                tsum += p;
            }
            #pragma unroll
            for (int off = 1; off < 16; off <<= 1)
                tsum += __shfl_xor(tsum, off);
            l[r] = l[r] * alpha[r] + tsum;
            m[r] = mn;
        }
        #pragma unroll
        for (int ct = 0; ct < 8; ++ct)
            #pragma unroll
            for (int r = 0; r < 4; ++r)
                o[ct][r] *= alpha[r];

        // ---- P: C-layout -> per-wave LDS -> A-layout ----
        unsigned short* pw = Pl[w];
        #pragma unroll
        for (int nt = 0; nt < 4; ++nt)
            #pragma unroll
            for (int r = 0; r < 4; ++r)
                pw[(quad * 4 + r) * 72 + nt * 16 + n16] = f2bf(s[nt][r]);

        // ---- O += P V ----
        #pragma unroll
        for (int kk2 = 0; kk2 < 2; ++kk2) {
            bf16x8 afr = *reinterpret_cast<const bf16x8*>(
                &pw[n16 * 72 + kk2 * 32 + quad * 8]);
            #pragma unroll
            for (int ct = 0; ct < 8; ++ct) {
                bf16x8 vf = *reinterpret_cast<const bf16x8*>(
                    &Vl[(ct * 16 + n16) * 72 + kk2 * 32 + quad * 8]);
                o[ct] = __builtin_amdgcn_mfma_f32_16x16x32_bf16(afr, vf, o[ct], 0, 0, 0);
            }
        }
    }

    if (qt < 8) {
        // single chunk: final fp32 output
        float* outp = out + (bT + qbase) * C_DIM;
        #pragma unroll
        for (int r = 0; r < 4; ++r) {
            float inv = 1.0f / l[r];
            #pragma unroll
            for (int ct = 0; ct < 8; ++ct)
                outp[(size_t)(quad * 4 + r) * C_DIM + ct * 16 + n16] = o[ct][r] * inv;
        }
    } else {
        // partial: full 16x128 per-wave stage in Kl (free after loop),
        // then fully-contiguous 1-KB-per-instruction stores
        __syncthreads();                   // all waves done reading Kl/Vl
        const int slot = b * 72 + chunk_base8(qt) + chunk;
        unsigned short* os = Kl + w * 2048;
        #pragma unroll
        for (int ct = 0; ct < 8; ++ct)
            #pragma unroll
            for (int r = 0; r < 4; ++r)
                os[(quad * 4 + r) * 128 + ct * 16 + n16] = f2bf(o[ct][r]);
        unsigned short* op = opart + (size_t)slot * 8192 + w * 2048;
        #pragma unroll
        for (int i = 0; i < 4; ++i) {
            int e = (lane + i * 64) * 8;
            *reinterpret_cast<uint4*>(op + e) =
                *reinterpret_cast<const uint4*>(os + e);
        }
        if (n16 == 0) {
            #pragma unroll
            for (int r = 0; r < 4; ++r)
                mlbuf[(size_t)slot * 64 + w * 16 + quad * 4 + r] =
                    make_float2(m[r], l[r]);
        }
    }
}

// ---------------------------------------------------------------------------
// merge: combine <=4 bf16 partials per (b, qt>=8). grid 192 (1D), coalesced:
// thread t owns cols (t&31)*4..+3 for rows (t>>5)*8 + ri.
// ---------------------------------------------------------------------------
__global__ __launch_bounds__(256) void merge_kernel(
    const unsigned short* __restrict__ opart, const float2* __restrict__ mlbuf,
    float* __restrict__ out)
{
    const int bid = blockIdx.x;
    const int b   = bid & 7;
    const int qt  = 8 + (bid >> 3);
    const int nch  = (qt >> 3) + 1;
    const int base = b * 72 + chunk_base8(qt);
    const int t    = threadIdx.x;
    const int colg = (t & 31) * 4;
    const int rowg = t >> 5;               // 0..7

    #pragma unroll
    for (int ri = 0; ri < 8; ++ri) {
        const int row = rowg * 8 + ri;
        float mi[4], li[4], wgt[4];
        float M = -INFINITY;
        for (int i = 0; i < nch; ++i) {
            float2 tm = mlbuf[(size_t)(base + i) * 64 + row];
            mi[i] = tm.x; li[i] = tm.y;
            M = fmaxf(M, tm.x);
        }
        float L = 0.f;
        for (int i = 0; i < nch; ++i) {
            wgt[i] = __expf(mi[i] - M);
            L += li[i] * wgt[i];
        }
        const float inv = 1.0f / L;

        float a0 = 0.f, a1 = 0.f, a2 = 0.f, a3 = 0.f;
        for (int i = 0; i < nch; ++i) {
            uint2 u = *reinterpret_cast<const uint2*>(
                opart + (size_t)(base + i) * 8192 + row * 128 + colg);
            union { unsigned int u; float f; } e0, e1, e2, e3;
            e0.u = (u.x & 0xFFFFu) << 16; e1.u = u.x & 0xFFFF0000u;
            e2.u = (u.y & 0xFFFFu) << 16; e3.u = u.y & 0xFFFF0000u;
            a0 += wgt[i] * e0.f; a1 += wgt[i] * e1.f;
            a2 += wgt[i] * e2.f; a3 += wgt[i] * e3.f;
        }
        float4 r4;
        r4.x = a0 * inv; r4.y = a1 * inv; r4.z = a2 * inv; r4.w = a3 * inv;
        *reinterpret_cast<float4*>(
            out + ((size_t)(b * T_SEQ + qt * 64 + row)) * C_DIM + colg) = r4;
    }
}

extern "C" void kernel_launch(void* const* d_in, const int* in_sizes, int n_in,
                              void* d_out, int out_size, void* d_ws, size_t ws_size,
                              hipStream_t stream) {
    const float* x  = (const float*)d_in[0];
    const float* Wk = (const float*)d_in[1];
    const float* Wq = (const float*)d_in[2];
    const float* Wv = (const float*)d_in[3];

    unsigned short* qw    = (unsigned short*)d_ws;
    unsigned short* kw    = qw + 2097152;
    unsigned short* vw    = kw + 2097152;
    unsigned short* opart = vw + 2097152;
    float2*         mlb   = (float2*)((char*)d_ws + ML_OFF);

    proj_kernel<<<768, 256, 0, stream>>>(x, Wq, Wk, Wv, qw, kw, vw);
    attn_kernel<<<1024, 256, 0, stream>>>(qw, kw, vw, opart, mlb, (float*)d_out);
    merge_kernel<<<192, 256, 0, stream>>>(opart, mlb, (float*)d_out);
}